// Round 7
// baseline (240.171 us; speedup 1.0000x reference)
//
#include <hip/hip_runtime.h>
#include <hip/hip_bf16.h>

typedef __bf16 bf16_t;
typedef __bf16 bf16x8 __attribute__((ext_vector_type(8)));
typedef __bf16 bf16x4 __attribute__((ext_vector_type(4)));
typedef float f32x4 __attribute__((ext_vector_type(4)));

#define B_DIM 8
#define C_DIM 512
#define T_DIM 1024
#define NH 8
#define HD 64

// ---------------------------------------------------------------------------
// Kernel 0: one-time weight conversion fp32 -> bf16.
// ---------------------------------------------------------------------------
__global__ __launch_bounds__(256) void prep_w(const float* __restrict__ w1,
                                              const float* __restrict__ w2,
                                              bf16_t* __restrict__ o1,
                                              bf16_t* __restrict__ o2)
{
    int tid = blockIdx.x * 256 + threadIdx.x;
    for (int p = 0; p < 4; ++p) {
        int q = tid + p * 65536;
        const f32x4* src;
        bf16x4* dst;
        int qq;
        if (q < 196608) { src = (const f32x4*)w1; dst = (bf16x4*)o1; qq = q; }
        else            { src = (const f32x4*)w2; dst = (bf16x4*)o2; qq = q - 196608; }
        f32x4 f = src[qq];
        bf16x4 h;
        for (int j = 0; j < 4; ++j) h[j] = (bf16_t)f[j];
        dst[qq] = h;
    }
}

// ---------------------------------------------------------------------------
// Kernel 1: GroupNorm.  x (b,c,t) fp32 -> n_t (b,t,c) bf16.  (HBM-bound,
// ~72 MB traffic ~= 11.4 us roofline -- already there; unchanged.)
// ---------------------------------------------------------------------------
__global__ __launch_bounds__(256) void gn_kernel(const float* __restrict__ x,
                                                 const float* __restrict__ gw,
                                                 const float* __restrict__ gb,
                                                 bf16_t* __restrict__ n_t)
{
    __shared__ bf16_t sX[16384];
    __shared__ float sred[8];
    int tid = threadIdx.x;
    int bb  = blockIdx.x >> 5;
    int g   = blockIdx.x & 31;
    const f32x4* xg4 = reinterpret_cast<const f32x4*>(x + (size_t)(bb * C_DIM + g * 16) * T_DIM);

    float s = 0.f, sq = 0.f;
    for (int i = 0; i < 16; ++i) {
        int v = tid + i * 256;
        f32x4 f = xg4[v];
        bf16x4 h;
        for (int j = 0; j < 4; ++j) {
            s += f[j]; sq += f[j] * f[j];
            h[j] = (bf16_t)f[j];
        }
        *reinterpret_cast<bf16x4*>(sX + v * 4) = h;
    }
    for (int off = 1; off < 64; off <<= 1) {
        s  += __shfl_xor(s, off);
        sq += __shfl_xor(sq, off);
    }
    int wv = tid >> 6;
    if ((tid & 63) == 0) { sred[wv * 2] = s; sred[wv * 2 + 1] = sq; }
    __syncthreads();
    s  = sred[0] + sred[2] + sred[4] + sred[6];
    sq = sred[1] + sred[3] + sred[5] + sred[7];
    float mean = s * (1.f / 16384.f);
    float var  = sq * (1.f / 16384.f) - mean * mean;
    float rs   = rsqrtf(var + 1e-5f);

    int hf = tid & 1;
    float aa[8], bbias[8];
    for (int j = 0; j < 8; ++j) {
        int c = hf * 8 + j;
        float av = gw[g * 16 + c] * rs;
        aa[j] = av;
        bbias[j] = gb[g * 16 + c] - mean * av;
    }
    bf16_t* ob = n_t + (size_t)bb * T_DIM * C_DIM + g * 16 + hf * 8;
    for (int p = 0; p < 8; ++p) {
        int t = (tid >> 1) + p * 128;
        bf16x8 o;
        for (int j = 0; j < 8; ++j) {
            float xv = (float)sX[(hf * 8 + j) * 1024 + t];
            o[j] = (bf16_t)(xv * aa[j] + bbias[j]);
        }
        *reinterpret_cast<bf16x8*>(ob + (size_t)t * C_DIM) = o;
    }
}

// ---------------------------------------------------------------------------
// Kernel 2: QKV GEMM (unchanged from round 6).
// ---------------------------------------------------------------------------
__global__ __launch_bounds__(256) void qkv_gemm_kernel(
    const bf16_t* __restrict__ wqb, const float* __restrict__ bq,
    const bf16_t* __restrict__ n_t, bf16_t* __restrict__ qkv)
{
    __shared__ bf16_t sA[64 * 72];
    __shared__ bf16_t sB[128 * 72];
    int tid = threadIdx.x;
    int w = tid >> 6, lane = tid & 63, quad = lane >> 4, l15 = lane & 15;
    int bx = blockIdx.x;          // 0..23  (= h*3 + type)
    int t0 = blockIdx.y * 128;
    int bb = blockIdx.z;
    int o0 = bx * 64;
    const bf16_t* Ab = wqb + (size_t)o0 * C_DIM;
    const bf16_t* Bb = n_t + ((size_t)bb * T_DIM + t0) * C_DIM;

    f32x4 acc[2][4];
    for (int mt = 0; mt < 2; ++mt)
        for (int nt = 0; nt < 4; ++nt)
            acc[mt][nt] = f32x4{0.f, 0.f, 0.f, 0.f};
    int mw0 = (w >> 1) * 32;
    int nw0 = (w & 1) * 64;

    for (int k0 = 0; k0 < C_DIM; k0 += 64) {
        for (int i = 0; i < 2; ++i) {
            int v = tid + i * 256;
            int row = v >> 3, c8 = v & 7;
            *reinterpret_cast<bf16x8*>(sA + row * 72 + c8 * 8) =
                *reinterpret_cast<const bf16x8*>(Ab + (size_t)row * C_DIM + k0 + c8 * 8);
        }
        for (int i = 0; i < 4; ++i) {
            int v = tid + i * 256;
            int row = v >> 3, c8 = v & 7;
            *reinterpret_cast<bf16x8*>(sB + row * 72 + c8 * 8) =
                *reinterpret_cast<const bf16x8*>(Bb + (size_t)row * C_DIM + k0 + c8 * 8);
        }
        __syncthreads();
        for (int kk = 0; kk < 2; ++kk) {
            bf16x8 af[2], bfr[4];
            for (int mt = 0; mt < 2; ++mt)
                af[mt] = *reinterpret_cast<const bf16x8*>(sA + (mw0 + mt * 16 + l15) * 72 + kk * 32 + quad * 8);
            for (int nt = 0; nt < 4; ++nt)
                bfr[nt] = *reinterpret_cast<const bf16x8*>(sB + (nw0 + nt * 16 + l15) * 72 + kk * 32 + quad * 8);
            for (int mt = 0; mt < 2; ++mt)
                for (int nt = 0; nt < 4; ++nt)
                    acc[mt][nt] = __builtin_amdgcn_mfma_f32_16x16x32_bf16(af[mt], bfr[nt], acc[mt][nt], 0, 0, 0);
        }
        __syncthreads();
    }

    int h = bx / 3, type = bx % 3;
    size_t base = ((size_t)(bb * NH + h) * 3 + type) * (64 * 1024);

    if (type < 2) {
        for (int mt = 0; mt < 2; ++mt)
            for (int nt = 0; nt < 4; ++nt)
                for (int r = 0; r < 4; ++r) {
                    int mw = mw0 + mt * 16 + quad * 4 + r;
                    int tl = nw0 + nt * 16 + l15;
                    float v = acc[mt][nt][r] + bq[o0 + mw];
                    sB[tl * 72 + mw] = (bf16_t)v;
                }
        __syncthreads();
        for (int i = 0; i < 4; ++i) {
            int v = tid + i * 256;
            int tl = v >> 3, c8 = v & 7;
            bf16x8 d = *reinterpret_cast<const bf16x8*>(sB + tl * 72 + c8 * 8);
            *reinterpret_cast<bf16x8*>(qkv + base + (size_t)(t0 + tl) * 64 + c8 * 8) = d;
        }
    } else {
        for (int mt = 0; mt < 2; ++mt)
            for (int nt = 0; nt < 4; ++nt)
                for (int r = 0; r < 4; ++r) {
                    int mw = mw0 + mt * 16 + quad * 4 + r;
                    int tl = nw0 + nt * 16 + l15;
                    float v = acc[mt][nt][r] + bq[o0 + mw];
                    sB[mw * 136 + tl] = (bf16_t)v;
                }
        __syncthreads();
        for (int i = 0; i < 4; ++i) {
            int v = tid + i * 256;
            int cc = v >> 4, t8 = (v & 15) * 8;
            bf16x8 d = *reinterpret_cast<const bf16x8*>(sB + cc * 136 + t8);
            *reinterpret_cast<bf16x8*>(qkv + base + (size_t)cc * 1024 + t0 + t8) = d;
        }
    }
}

// ---------------------------------------------------------------------------
// Kernel 3: flash attention, round 7 -- BARRIER-FREE.
// K and V are read directly from global as MFMA fragments (b128/lane);
// per-head K/V (256 KB) is L2-resident on one XCD via the (bh, qt) grid.
// Q-fragments hoisted to registers.  Only LDS: wave-private P (t,s) buffer
// (C-layout -> B-fragment round trip) + 4x16 rowsum patch.  No __syncthreads.
// PV computed as O^T = V . P^T  (A=V-frag (c,s), B=P-frag (t,s)), so the
// epilogue stores 4x 8B per lane instead of 16 scalar u16.
// ---------------------------------------------------------------------------
__global__ __launch_bounds__(256, 4) void attn_kernel(const bf16_t* __restrict__ qkv,
                                                      bf16_t* __restrict__ net_t)
{
    __shared__ bf16_t sP[4][16 * 72];
    __shared__ float  sL[4][16];
    int tid = threadIdx.x;
    int w = tid >> 6, lane = tid & 63, quad = lane >> 4, l15 = lane & 15;
    int bh = blockIdx.x;
    int qt = blockIdx.y;
    size_t qb = (size_t)bh * 3 * 65536;
    const bf16_t* Qg = qkv + qb + (size_t)qt * 4096;
    const bf16_t* Kg = qkv + qb + 65536;
    const bf16_t* Vg = qkv + qb + 2 * 65536;
    const float K2 = 0.125f * 1.44269504088896f;   // scale^2 * log2(e)

    // Q A-fragment for this wave's 16 q-rows, held in registers for all tiles
    bf16x8 qf[2];
    for (int kk = 0; kk < 2; ++kk)
        qf[kk] = *reinterpret_cast<const bf16x8*>(Qg + (size_t)(w * 16 + l15) * 64 + kk * 32 + quad * 8);

    f32x4 O[4];
    for (int i = 0; i < 4; ++i) O[i] = f32x4{0.f, 0.f, 0.f, 0.f};
    float lsum[4] = {0.f, 0.f, 0.f, 0.f};
    bf16_t* sPw = sP[w];

    for (int st = 0; st < 16; ++st) {
        int s0 = st * 64;

        // ---- S = Q K^T : K fragments straight from global (L2-hot) ----
        f32x4 Sacc[4];
        for (int nt = 0; nt < 4; ++nt) Sacc[nt] = f32x4{0.f, 0.f, 0.f, 0.f};
        for (int kk = 0; kk < 2; ++kk)
            for (int nt = 0; nt < 4; ++nt) {
                bf16x8 kf = *reinterpret_cast<const bf16x8*>(
                    Kg + (size_t)(s0 + nt * 16 + l15) * 64 + kk * 32 + quad * 8);
                Sacc[nt] = __builtin_amdgcn_mfma_f32_16x16x32_bf16(qf[kk], kf, Sacc[nt], 0, 0, 0);
            }

        // ---- unnormalized exp -> wave-private LDS (t,s) ----
        for (int nt = 0; nt < 4; ++nt)
            for (int r = 0; r < 4; ++r) {
                float p = exp2f(Sacc[nt][r] * K2);
                lsum[r] += p;
                sPw[(quad * 4 + r) * 72 + nt * 16 + l15] = (bf16_t)p;
            }

        // ---- O^T += V . P^T : V fragments straight from global ----
        bf16x8 pf[2];
        for (int ks = 0; ks < 2; ++ks)
            pf[ks] = *reinterpret_cast<const bf16x8*>(sPw + l15 * 72 + ks * 32 + quad * 8);
        for (int ks = 0; ks < 2; ++ks)
            for (int mt = 0; mt < 4; ++mt) {
                bf16x8 vf = *reinterpret_cast<const bf16x8*>(
                    Vg + (size_t)(mt * 16 + l15) * 1024 + s0 + ks * 32 + quad * 8);
                O[mt] = __builtin_amdgcn_mfma_f32_16x16x32_bf16(vf, pf[ks], O[mt], 0, 0, 0);
            }
    }

    // rowsums: lane holds partial for t=quad*4+r over s=16 lanes -> reduce,
    // then transpose (quad,r) -> l15 through a tiny LDS patch.
    for (int r = 0; r < 4; ++r) {
        float l = lsum[r];
        for (int off = 1; off < 16; off <<= 1) l += __shfl_xor(l, off);
        if (l15 == 0) sL[w][quad * 4 + r] = l;
    }
    float inv = 1.f / sL[w][l15];

    // O^T layout: lane holds t = w*16+l15 (col), c = mt*16+quad*4+r (row)
    int bb = bh >> 3, h = bh & 7;
    int t = qt * 64 + w * 16 + l15;
    bf16_t* orow = net_t + ((size_t)bb * T_DIM + t) * C_DIM + h * 64;
    for (int mt = 0; mt < 4; ++mt) {
        bf16x4 o4;
        for (int r = 0; r < 4; ++r) o4[r] = (bf16_t)(O[mt][r] * inv);
        *reinterpret_cast<bf16x4*>(orow + mt * 16 + quad * 4) = o4;
    }
}

// ---------------------------------------------------------------------------
// Kernel 4: out GEMM + bias + residual (unchanged from round 6).
// ---------------------------------------------------------------------------
__global__ __launch_bounds__(256) void out_gemm_kernel(
    const bf16_t* __restrict__ wob, const float* __restrict__ bo,
    const bf16_t* __restrict__ net_t, const float* __restrict__ x,
    float* __restrict__ out)
{
    __shared__ bf16_t sA[64 * 72];
    __shared__ bf16_t sB[128 * 72];
    int tid = threadIdx.x;
    int w = tid >> 6, lane = tid & 63, quad = lane >> 4, l15 = lane & 15;
    int o0 = blockIdx.x * 64;
    int t0 = blockIdx.y * 128;
    int bb = blockIdx.z;
    const bf16_t* Ab = wob + (size_t)o0 * C_DIM;
    const bf16_t* Bb = net_t + ((size_t)bb * T_DIM + t0) * C_DIM;

    f32x4 acc[2][4];
    for (int mt = 0; mt < 2; ++mt)
        for (int nt = 0; nt < 4; ++nt)
            acc[mt][nt] = f32x4{0.f, 0.f, 0.f, 0.f};
    int mw0 = (w >> 1) * 32;
    int nw0 = (w & 1) * 64;

    for (int k0 = 0; k0 < C_DIM; k0 += 64) {
        for (int i = 0; i < 2; ++i) {
            int v = tid + i * 256;
            int row = v >> 3, c8 = v & 7;
            *reinterpret_cast<bf16x8*>(sA + row * 72 + c8 * 8) =
                *reinterpret_cast<const bf16x8*>(Ab + (size_t)row * C_DIM + k0 + c8 * 8);
        }
        for (int i = 0; i < 4; ++i) {
            int v = tid + i * 256;
            int row = v >> 3, c8 = v & 7;
            *reinterpret_cast<bf16x8*>(sB + row * 72 + c8 * 8) =
                *reinterpret_cast<const bf16x8*>(Bb + (size_t)row * C_DIM + k0 + c8 * 8);
        }
        __syncthreads();
        for (int kk = 0; kk < 2; ++kk) {
            bf16x8 af[2], bfr[4];
            for (int mt = 0; mt < 2; ++mt)
                af[mt] = *reinterpret_cast<const bf16x8*>(sA + (mw0 + mt * 16 + l15) * 72 + kk * 32 + quad * 8);
            for (int nt = 0; nt < 4; ++nt)
                bfr[nt] = *reinterpret_cast<const bf16x8*>(sB + (nw0 + nt * 16 + l15) * 72 + kk * 32 + quad * 8);
            for (int mt = 0; mt < 2; ++mt)
                for (int nt = 0; nt < 4; ++nt)
                    acc[mt][nt] = __builtin_amdgcn_mfma_f32_16x16x32_bf16(af[mt], bfr[nt], acc[mt][nt], 0, 0, 0);
        }
        __syncthreads();
    }

    for (int mt = 0; mt < 2; ++mt)
        for (int nt = 0; nt < 4; ++nt)
            for (int r = 0; r < 4; ++r) {
                int o = o0 + mw0 + mt * 16 + quad * 4 + r;
                int t = t0 + nw0 + nt * 16 + l15;
                size_t idx = ((size_t)bb * C_DIM + o) * T_DIM + t;
                out[idx] = acc[mt][nt][r] + bo[o] + x[idx];
            }
}

// ---------------------------------------------------------------------------
extern "C" void kernel_launch(void* const* d_in, const int* in_sizes, int n_in,
                              void* d_out, int out_size, void* d_ws, size_t ws_size,
                              hipStream_t stream)
{
    const float* x     = (const float*)d_in[0];
    const float* gn_w  = (const float*)d_in[1];
    const float* gn_b  = (const float*)d_in[2];
    const float* qkv_w = (const float*)d_in[3];
    const float* qkv_b = (const float*)d_in[4];
    const float* out_w = (const float*)d_in[5];
    const float* out_b = (const float*)d_in[6];
    float* out = (float*)d_out;

    // ws layout (bf16): n_t 8MB | qkv 24MB | net_t 8MB | wqb 1.5MB | wob 0.5MB
    char* ws = (char*)d_ws;
    bf16_t* n_t   = (bf16_t*)(ws);
    bf16_t* qkv   = (bf16_t*)(ws + 8388608);
    bf16_t* net_t = (bf16_t*)(ws + 33554432);
    bf16_t* wqb   = (bf16_t*)(ws + 41943040);
    bf16_t* wob   = (bf16_t*)(ws + 41943040 + 1572864);

    prep_w<<<dim3(256), 256, 0, stream>>>(qkv_w, out_w, wqb, wob);
    gn_kernel<<<dim3(256), 256, 0, stream>>>(x, gn_w, gn_b, n_t);
    qkv_gemm_kernel<<<dim3(24, 8, 8), 256, 0, stream>>>(wqb, qkv_b, n_t, qkv);
    attn_kernel<<<dim3(64, 16), 256, 0, stream>>>(qkv, net_t);
    out_gemm_kernel<<<dim3(8, 8, 8), 256, 0, stream>>>(wob, out_b, net_t, x, out);
}

// Round 9
// 162.508 us; speedup vs baseline: 1.4779x; 1.4779x over previous
//
#include <hip/hip_runtime.h>
#include <hip/hip_bf16.h>

typedef __bf16 bf16_t;
typedef __bf16 bf16x8 __attribute__((ext_vector_type(8)));
typedef __bf16 bf16x4 __attribute__((ext_vector_type(4)));
typedef short  s16x4  __attribute__((ext_vector_type(4)));
typedef float  f32x4  __attribute__((ext_vector_type(4)));

#define B_DIM 8
#define C_DIM 512
#define T_DIM 1024
#define NH 8
#define HD 64

// v_mfma_f32_16x16x16_bf16 (gfx950 ISA §10): A/B = 4 bf16 (2 VGPRs),
// operand layout k=quad*4+j, m/n=l15; C row=quad*4+r, col=l15.
__device__ __forceinline__ f32x4 mfma16_bf16(bf16x4 a, bf16x4 b, f32x4 c) {
    return __builtin_amdgcn_mfma_f32_16x16x16bf16_1k(
        __builtin_bit_cast(s16x4, a), __builtin_bit_cast(s16x4, b), c, 0, 0, 0);
}

// ---------------------------------------------------------------------------
// Kernel 0: one-time weight conversion fp32 -> bf16.
// ---------------------------------------------------------------------------
__global__ __launch_bounds__(256) void prep_w(const float* __restrict__ w1,
                                              const float* __restrict__ w2,
                                              bf16_t* __restrict__ o1,
                                              bf16_t* __restrict__ o2)
{
    int tid = blockIdx.x * 256 + threadIdx.x;
    for (int p = 0; p < 4; ++p) {
        int q = tid + p * 65536;
        const f32x4* src;
        bf16x4* dst;
        int qq;
        if (q < 196608) { src = (const f32x4*)w1; dst = (bf16x4*)o1; qq = q; }
        else            { src = (const f32x4*)w2; dst = (bf16x4*)o2; qq = q - 196608; }
        f32x4 f = src[qq];
        bf16x4 h;
        for (int j = 0; j < 4; ++j) h[j] = (bf16_t)f[j];
        dst[qq] = h;
    }
}

// ---------------------------------------------------------------------------
// Kernel 1: GroupNorm.  x (b,c,t) fp32 -> n_t (b,t,c) bf16.  (unchanged)
// ---------------------------------------------------------------------------
__global__ __launch_bounds__(256) void gn_kernel(const float* __restrict__ x,
                                                 const float* __restrict__ gw,
                                                 const float* __restrict__ gb,
                                                 bf16_t* __restrict__ n_t)
{
    __shared__ bf16_t sX[16384];
    __shared__ float sred[8];
    int tid = threadIdx.x;
    int bb  = blockIdx.x >> 5;
    int g   = blockIdx.x & 31;
    const f32x4* xg4 = reinterpret_cast<const f32x4*>(x + (size_t)(bb * C_DIM + g * 16) * T_DIM);

    float s = 0.f, sq = 0.f;
    for (int i = 0; i < 16; ++i) {
        int v = tid + i * 256;
        f32x4 f = xg4[v];
        bf16x4 h;
        for (int j = 0; j < 4; ++j) {
            s += f[j]; sq += f[j] * f[j];
            h[j] = (bf16_t)f[j];
        }
        *reinterpret_cast<bf16x4*>(sX + v * 4) = h;
    }
    for (int off = 1; off < 64; off <<= 1) {
        s  += __shfl_xor(s, off);
        sq += __shfl_xor(sq, off);
    }
    int wv = tid >> 6;
    if ((tid & 63) == 0) { sred[wv * 2] = s; sred[wv * 2 + 1] = sq; }
    __syncthreads();
    s  = sred[0] + sred[2] + sred[4] + sred[6];
    sq = sred[1] + sred[3] + sred[5] + sred[7];
    float mean = s * (1.f / 16384.f);
    float var  = sq * (1.f / 16384.f) - mean * mean;
    float rs   = rsqrtf(var + 1e-5f);

    int hf = tid & 1;
    float aa[8], bbias[8];
    for (int j = 0; j < 8; ++j) {
        int c = hf * 8 + j;
        float av = gw[g * 16 + c] * rs;
        aa[j] = av;
        bbias[j] = gb[g * 16 + c] - mean * av;
    }
    bf16_t* ob = n_t + (size_t)bb * T_DIM * C_DIM + g * 16 + hf * 8;
    for (int p = 0; p < 8; ++p) {
        int t = (tid >> 1) + p * 128;
        bf16x8 o;
        for (int j = 0; j < 8; ++j) {
            float xv = (float)sX[(hf * 8 + j) * 1024 + t];
            o[j] = (bf16_t)(xv * aa[j] + bbias[j]);
        }
        *reinterpret_cast<bf16x8*>(ob + (size_t)t * C_DIM) = o;
    }
}

// ---------------------------------------------------------------------------
// Kernel 2: QKV GEMM (unchanged from round 6).
// ---------------------------------------------------------------------------
__global__ __launch_bounds__(256) void qkv_gemm_kernel(
    const bf16_t* __restrict__ wqb, const float* __restrict__ bq,
    const bf16_t* __restrict__ n_t, bf16_t* __restrict__ qkv)
{
    __shared__ bf16_t sA[64 * 72];
    __shared__ bf16_t sB[128 * 72];
    int tid = threadIdx.x;
    int w = tid >> 6, lane = tid & 63, quad = lane >> 4, l15 = lane & 15;
    int bx = blockIdx.x;          // 0..23  (= h*3 + type)
    int t0 = blockIdx.y * 128;
    int bb = blockIdx.z;
    int o0 = bx * 64;
    const bf16_t* Ab = wqb + (size_t)o0 * C_DIM;
    const bf16_t* Bb = n_t + ((size_t)bb * T_DIM + t0) * C_DIM;

    f32x4 acc[2][4];
    for (int mt = 0; mt < 2; ++mt)
        for (int nt = 0; nt < 4; ++nt)
            acc[mt][nt] = f32x4{0.f, 0.f, 0.f, 0.f};
    int mw0 = (w >> 1) * 32;
    int nw0 = (w & 1) * 64;

    for (int k0 = 0; k0 < C_DIM; k0 += 64) {
        for (int i = 0; i < 2; ++i) {
            int v = tid + i * 256;
            int row = v >> 3, c8 = v & 7;
            *reinterpret_cast<bf16x8*>(sA + row * 72 + c8 * 8) =
                *reinterpret_cast<const bf16x8*>(Ab + (size_t)row * C_DIM + k0 + c8 * 8);
        }
        for (int i = 0; i < 4; ++i) {
            int v = tid + i * 256;
            int row = v >> 3, c8 = v & 7;
            *reinterpret_cast<bf16x8*>(sB + row * 72 + c8 * 8) =
                *reinterpret_cast<const bf16x8*>(Bb + (size_t)row * C_DIM + k0 + c8 * 8);
        }
        __syncthreads();
        for (int kk = 0; kk < 2; ++kk) {
            bf16x8 af[2], bfr[4];
            for (int mt = 0; mt < 2; ++mt)
                af[mt] = *reinterpret_cast<const bf16x8*>(sA + (mw0 + mt * 16 + l15) * 72 + kk * 32 + quad * 8);
            for (int nt = 0; nt < 4; ++nt)
                bfr[nt] = *reinterpret_cast<const bf16x8*>(sB + (nw0 + nt * 16 + l15) * 72 + kk * 32 + quad * 8);
            for (int mt = 0; mt < 2; ++mt)
                for (int nt = 0; nt < 4; ++nt)
                    acc[mt][nt] = __builtin_amdgcn_mfma_f32_16x16x32_bf16(af[mt], bfr[nt], acc[mt][nt], 0, 0, 0);
        }
        __syncthreads();
    }

    int h = bx / 3, type = bx % 3;
    size_t base = ((size_t)(bb * NH + h) * 3 + type) * (64 * 1024);

    if (type < 2) {
        for (int mt = 0; mt < 2; ++mt)
            for (int nt = 0; nt < 4; ++nt)
                for (int r = 0; r < 4; ++r) {
                    int mw = mw0 + mt * 16 + quad * 4 + r;
                    int tl = nw0 + nt * 16 + l15;
                    float v = acc[mt][nt][r] + bq[o0 + mw];
                    sB[tl * 72 + mw] = (bf16_t)v;
                }
        __syncthreads();
        for (int i = 0; i < 4; ++i) {
            int v = tid + i * 256;
            int tl = v >> 3, c8 = v & 7;
            bf16x8 d = *reinterpret_cast<const bf16x8*>(sB + tl * 72 + c8 * 8);
            *reinterpret_cast<bf16x8*>(qkv + base + (size_t)(t0 + tl) * 64 + c8 * 8) = d;
        }
    } else {
        for (int mt = 0; mt < 2; ++mt)
            for (int nt = 0; nt < 4; ++nt)
                for (int r = 0; r < 4; ++r) {
                    int mw = mw0 + mt * 16 + quad * 4 + r;
                    int tl = nw0 + nt * 16 + l15;
                    float v = acc[mt][nt][r] + bq[o0 + mw];
                    sB[mw * 136 + tl] = (bf16_t)v;
                }
        __syncthreads();
        for (int i = 0; i < 4; ++i) {
            int v = tid + i * 256;
            int cc = v >> 4, t8 = (v & 15) * 8;
            bf16x8 d = *reinterpret_cast<const bf16x8*>(sB + cc * 136 + t8);
            *reinterpret_cast<bf16x8*>(qkv + base + (size_t)cc * 1024 + t0 + t8) = d;
        }
    }
}

// ---------------------------------------------------------------------------
// Kernel 3: flash attention, round 9 (= R8 design, fixed builtin).
// LDS staging of K/V (R6 structure: shared by 4 waves, reg prefetch,
// 2 barriers/tile) but the P matrix NEVER touches LDS:
//   S^T = K.Q^T   (C-layout: s=quad*4+r, t=l15)
//   exp -> bf16x4 == operand layout of v_mfma_f32_16x16x16_bf16 (k=quad*4+j)
//   O^T += V.P^T  (A=V from sV (c,s), B=P in registers)
// Row-sums: one scalar/lane + 2 shuffles at the end.  LDS 18.4 KB -> 6 blk/CU.
// ---------------------------------------------------------------------------
__global__ __launch_bounds__(256, 6) void attn_kernel(const bf16_t* __restrict__ qkv,
                                                      bf16_t* __restrict__ net_t)
{
    __shared__ bf16_t sK[64 * 72];
    __shared__ bf16_t sV[64 * 72];      // (c=64 rows, s=64 cols)
    int tid = threadIdx.x;
    int w = tid >> 6, lane = tid & 63, quad = lane >> 4, l15 = lane & 15;
    int bh = blockIdx.x;
    int qt = blockIdx.y;
    size_t qb = (size_t)bh * 3 * 65536;
    const bf16_t* Qg = qkv + qb + (size_t)qt * 4096;
    const bf16_t* Kg = qkv + qb + 65536;
    const bf16_t* Vg = qkv + qb + 2 * 65536;
    const float K2 = 0.125f * 1.44269504088896f;   // scale^2 * log2(e)

    // Q as B-operand (n=t=l15 within wave's 16 rows, k=c), registers for all tiles
    bf16x8 qf[2];
    for (int kk = 0; kk < 2; ++kk)
        qf[kk] = *reinterpret_cast<const bf16x8*>(Qg + (size_t)(w * 16 + l15) * 64 + kk * 32 + quad * 8);

    // prefetch K/V tile 0
    bf16x8 kreg[2], vreg[2];
    for (int i = 0; i < 2; ++i) {
        int v = tid + i * 256;
        kreg[i] = *reinterpret_cast<const bf16x8*>(Kg + (size_t)(v >> 3) * 64 + (v & 7) * 8);
        vreg[i] = *reinterpret_cast<const bf16x8*>(Vg + (size_t)(v >> 3) * 1024 + (v & 7) * 8);
    }

    f32x4 O[4];   // O^T: [ct] rows c=ct*16+quad*4+r, col t=l15
    for (int i = 0; i < 4; ++i) O[i] = f32x4{0.f, 0.f, 0.f, 0.f};
    float lsum = 0.f;

    for (int st = 0; st < 16; ++st) {
        __syncthreads();
        for (int i = 0; i < 2; ++i) {
            int v = tid + i * 256;
            *reinterpret_cast<bf16x8*>(sK + (v >> 3) * 72 + (v & 7) * 8) = kreg[i];
            *reinterpret_cast<bf16x8*>(sV + (v >> 3) * 72 + (v & 7) * 8) = vreg[i];
        }
        __syncthreads();
        if (st < 15) {
            int s0n = (st + 1) * 64;
            for (int i = 0; i < 2; ++i) {
                int v = tid + i * 256;
                kreg[i] = *reinterpret_cast<const bf16x8*>(Kg + (size_t)(s0n + (v >> 3)) * 64 + (v & 7) * 8);
                vreg[i] = *reinterpret_cast<const bf16x8*>(Vg + (size_t)(v >> 3) * 1024 + s0n + (v & 7) * 8);
            }
        }

        for (int mt = 0; mt < 4; ++mt) {
            // ---- S^T = K.Q^T for s-subtile mt (A=K rows s_local=l15) ----
            f32x4 S = f32x4{0.f, 0.f, 0.f, 0.f};
            for (int kk = 0; kk < 2; ++kk) {
                bf16x8 kf = *reinterpret_cast<const bf16x8*>(sK + (mt * 16 + l15) * 72 + kk * 32 + quad * 8);
                S = __builtin_amdgcn_mfma_f32_16x16x32_bf16(kf, qf[kk], S, 0, 0, 0);
            }
            // ---- exp in-register; pack directly as K=16 operand (k=quad*4+r) ----
            bf16x4 pf;
            for (int r = 0; r < 4; ++r) {
                float p = exp2f(S[r] * K2);
                lsum += p;
                pf[r] = (bf16_t)p;
            }
            // ---- O^T += V.P^T (contraction over 16 s; A=V rows c=l15) ----
            for (int ct = 0; ct < 4; ++ct) {
                bf16x4 vf = *reinterpret_cast<const bf16x4*>(sV + (ct * 16 + l15) * 72 + mt * 16 + quad * 4);
                O[ct] = mfma16_bf16(vf, pf, O[ct]);
            }
        }
    }

    // lane's lsum covers s=quad*4+r (all tiles) for t=l15: reduce over quads.
    lsum += __shfl_xor(lsum, 16);
    lsum += __shfl_xor(lsum, 32);
    float inv = 1.f / lsum;

    int bb = bh >> 3, h = bh & 7;
    int t = qt * 64 + w * 16 + l15;
    bf16_t* orow = net_t + ((size_t)bb * T_DIM + t) * C_DIM + h * 64;
    for (int ct = 0; ct < 4; ++ct) {
        bf16x4 o4;
        for (int r = 0; r < 4; ++r) o4[r] = (bf16_t)(O[ct][r] * inv);
        *reinterpret_cast<bf16x4*>(orow + ct * 16 + quad * 4) = o4;
    }
}

// ---------------------------------------------------------------------------
// Kernel 4: out GEMM + bias + residual (unchanged from round 6).
// ---------------------------------------------------------------------------
__global__ __launch_bounds__(256) void out_gemm_kernel(
    const bf16_t* __restrict__ wob, const float* __restrict__ bo,
    const bf16_t* __restrict__ net_t, const float* __restrict__ x,
    float* __restrict__ out)
{
    __shared__ bf16_t sA[64 * 72];
    __shared__ bf16_t sB[128 * 72];
    int tid = threadIdx.x;
    int w = tid >> 6, lane = tid & 63, quad = lane >> 4, l15 = lane & 15;
    int o0 = blockIdx.x * 64;
    int t0 = blockIdx.y * 128;
    int bb = blockIdx.z;
    const bf16_t* Ab = wob + (size_t)o0 * C_DIM;
    const bf16_t* Bb = net_t + ((size_t)bb * T_DIM + t0) * C_DIM;

    f32x4 acc[2][4];
    for (int mt = 0; mt < 2; ++mt)
        for (int nt = 0; nt < 4; ++nt)
            acc[mt][nt] = f32x4{0.f, 0.f, 0.f, 0.f};
    int mw0 = (w >> 1) * 32;
    int nw0 = (w & 1) * 64;

    for (int k0 = 0; k0 < C_DIM; k0 += 64) {
        for (int i = 0; i < 2; ++i) {
            int v = tid + i * 256;
            int row = v >> 3, c8 = v & 7;
            *reinterpret_cast<bf16x8*>(sA + row * 72 + c8 * 8) =
                *reinterpret_cast<const bf16x8*>(Ab + (size_t)row * C_DIM + k0 + c8 * 8);
        }
        for (int i = 0; i < 4; ++i) {
            int v = tid + i * 256;
            int row = v >> 3, c8 = v & 7;
            *reinterpret_cast<bf16x8*>(sB + row * 72 + c8 * 8) =
                *reinterpret_cast<const bf16x8*>(Bb + (size_t)row * C_DIM + k0 + c8 * 8);
        }
        __syncthreads();
        for (int kk = 0; kk < 2; ++kk) {
            bf16x8 af[2], bfr[4];
            for (int mt = 0; mt < 2; ++mt)
                af[mt] = *reinterpret_cast<const bf16x8*>(sA + (mw0 + mt * 16 + l15) * 72 + kk * 32 + quad * 8);
            for (int nt = 0; nt < 4; ++nt)
                bfr[nt] = *reinterpret_cast<const bf16x8*>(sB + (nw0 + nt * 16 + l15) * 72 + kk * 32 + quad * 8);
            for (int mt = 0; mt < 2; ++mt)
                for (int nt = 0; nt < 4; ++nt)
                    acc[mt][nt] = __builtin_amdgcn_mfma_f32_16x16x32_bf16(af[mt], bfr[nt], acc[mt][nt], 0, 0, 0);
        }
        __syncthreads();
    }

    for (int mt = 0; mt < 2; ++mt)
        for (int nt = 0; nt < 4; ++nt)
            for (int r = 0; r < 4; ++r) {
                int o = o0 + mw0 + mt * 16 + quad * 4 + r;
                int t = t0 + nw0 + nt * 16 + l15;
                size_t idx = ((size_t)bb * C_DIM + o) * T_DIM + t;
                out[idx] = acc[mt][nt][r] + bo[o] + x[idx];
            }
}

// ---------------------------------------------------------------------------
extern "C" void kernel_launch(void* const* d_in, const int* in_sizes, int n_in,
                              void* d_out, int out_size, void* d_ws, size_t ws_size,
                              hipStream_t stream)
{
    const float* x     = (const float*)d_in[0];
    const float* gn_w  = (const float*)d_in[1];
    const float* gn_b  = (const float*)d_in[2];
    const float* qkv_w = (const float*)d_in[3];
    const float* qkv_b = (const float*)d_in[4];
    const float* out_w = (const float*)d_in[5];
    const float* out_b = (const float*)d_in[6];
    float* out = (float*)d_out;

    // ws layout (bf16): n_t 8MB | qkv 24MB | net_t 8MB | wqb 1.5MB | wob 0.5MB
    char* ws = (char*)d_ws;
    bf16_t* n_t   = (bf16_t*)(ws);
    bf16_t* qkv   = (bf16_t*)(ws + 8388608);
    bf16_t* net_t = (bf16_t*)(ws + 33554432);
    bf16_t* wqb   = (bf16_t*)(ws + 41943040);
    bf16_t* wob   = (bf16_t*)(ws + 41943040 + 1572864);

    prep_w<<<dim3(256), 256, 0, stream>>>(qkv_w, out_w, wqb, wob);
    gn_kernel<<<dim3(256), 256, 0, stream>>>(x, gn_w, gn_b, n_t);
    qkv_gemm_kernel<<<dim3(24, 8, 8), 256, 0, stream>>>(wqb, qkv_b, n_t, qkv);
    attn_kernel<<<dim3(64, 16), 256, 0, stream>>>(qkv, net_t);
    out_gemm_kernel<<<dim3(8, 8, 8), 256, 0, stream>>>(wob, out_b, net_t, x, out);
}